// Round 1
// baseline (810.966 us; speedup 1.0000x reference)
//
#include <hip/hip_runtime.h>
#include <math.h>

#define NN 50000
#define EE 800000
#define JTOT 384   // 256 feat + 128 mz

// ---------------- prep: zero degree counts + transpose merger_w ----------------
__global__ void prep_kernel(int* counts, const float* merger_w, float* mwT) {
    int i = blockIdx.x * blockDim.x + threadIdx.x;
    if (i < NN) counts[i] = 0;
    if (i < 192 * 64) {
        int r = i >> 6, c = i & 63;
        mwT[i] = merger_w[c * 192 + r];   // mwT[i][j] = merger_w[j][i]
    }
}

// ---------------- CSR build ----------------
__global__ void count_kernel(const int* __restrict__ dst, int* counts) {
    for (int i = blockIdx.x * blockDim.x + threadIdx.x; i < EE; i += gridDim.x * blockDim.x)
        atomicAdd(&counts[dst[i]], 1);
}

__global__ __launch_bounds__(1024) void scan_kernel(const int* __restrict__ counts,
                                                    int* row_start, int* cursor) {
    __shared__ int sm[1024];
    const int per = (NN + 1023) / 1024;   // 49
    int t = threadIdx.x;
    int base = t * per;
    int s = 0;
    for (int i = 0; i < per; ++i) {
        int idx = base + i;
        if (idx < NN) s += counts[idx];
    }
    sm[t] = s;
    __syncthreads();
    for (int off = 1; off < 1024; off <<= 1) {
        int v = (t >= off) ? sm[t - off] : 0;
        __syncthreads();
        sm[t] += v;
        __syncthreads();
    }
    int run = sm[t] - s;   // exclusive prefix of this chunk
    for (int i = 0; i < per; ++i) {
        int idx = base + i;
        if (idx < NN) {
            row_start[idx] = run;
            cursor[idx] = run;
            run += counts[idx];
        }
    }
    if (t == 1023) row_start[NN] = sm[1023];
}

__global__ void scatter_kernel(const int* __restrict__ src, const int* __restrict__ dst,
                               const float* __restrict__ weight, int* cursor,
                               int* src_sorted, float* w_sorted) {
    for (int i = blockIdx.x * blockDim.x + threadIdx.x; i < EE; i += gridDim.x * blockDim.x) {
        int pos = atomicAdd(&cursor[dst[i]], 1);
        src_sorted[pos] = src[i];
        w_sorted[pos] = weight[i];
    }
}

// ---------------- fused GEMM: y[n][0:256]=feat, y[n][256:384]=mz ----------------
__global__ __launch_bounds__(256) void gemm_kernel(const float* __restrict__ x,
                                                   const float* __restrict__ fc_w,
                                                   const float* __restrict__ gate_m_w,
                                                   const float* __restrict__ gate_m_b,
                                                   float* __restrict__ y) {
    __shared__ float wl[64 * 129];   // 64 rows x 128, pad 129 -> conflict-free
    int jc = blockIdx.y;             // 0..5 (chunk of 64 output cols)
    int tid = threadIdx.x;
    for (int t = tid; t < 64 * 128; t += 256) {
        int jl = t >> 7, k = t & 127;
        int jg = jc * 64 + jl;
        float v = (jg < 256) ? fc_w[jg * 128 + k] : gate_m_w[(jg - 256) * 128 + k];
        wl[jl * 129 + k] = v;
    }
    __syncthreads();
    int jl = tid & 63, wv = tid >> 6;
    int jg = jc * 64 + jl;
    float bias = (jg >= 256) ? gate_m_b[jg - 256] : 0.0f;
    const float* wr = &wl[jl * 129];
    for (int g = blockIdx.x; g < NN / 4; g += gridDim.x) {
        int n = g * 4 + wv;
        const float4* xv = (const float4*)(x + (size_t)n * 128);
        float acc = bias;
        #pragma unroll
        for (int k4 = 0; k4 < 32; ++k4) {
            float4 v = xv[k4];
            acc += v.x * wr[4 * k4] + v.y * wr[4 * k4 + 1] + v.z * wr[4 * k4 + 2] + v.w * wr[4 * k4 + 3];
        }
        y[(size_t)n * JTOT + jg] = acc;
    }
}

// ---------------- el/er per node ----------------
__global__ __launch_bounds__(256) void elr_kernel(const float* __restrict__ y,
                                                  const float* __restrict__ attn_l,
                                                  const float* __restrict__ attn_r,
                                                  float* el, float* er) {
    int lane = threadIdx.x & 63, wv = threadIdx.x >> 6;
    int n = blockIdx.x * 4 + wv;
    if (n >= NN) return;
    const float* f = y + (size_t)n * JTOT;
    float pl[4], pr[4];
    #pragma unroll
    for (int h = 0; h < 4; ++h) {
        float fv = f[h * 64 + lane];
        pl[h] = fv * attn_l[h * 64 + lane];
        pr[h] = fv * attn_r[h * 64 + lane];
    }
    #pragma unroll
    for (int h = 0; h < 4; ++h) {
        #pragma unroll
        for (int o = 1; o < 64; o <<= 1) {
            pl[h] += __shfl_xor(pl[h], o, 64);
            pr[h] += __shfl_xor(pr[h], o, 64);
        }
    }
    if (lane == 0) {
        ((float4*)el)[n] = make_float4(pl[0], pl[1], pl[2], pl[3]);
        ((float4*)er)[n] = make_float4(pr[0], pr[1], pr[2], pr[3]);
    }
}

// ---------------- main per-node aggregation + gate + merger ----------------
__global__ __launch_bounds__(256) void node_kernel(const float* __restrict__ x,
                                                   const float* __restrict__ y,
                                                   const float* __restrict__ el,
                                                   const float* __restrict__ er,
                                                   const int* __restrict__ row_start,
                                                   const int* __restrict__ src_sorted,
                                                   const float* __restrict__ w_sorted,
                                                   const float* __restrict__ gate_fn_w,
                                                   const float* __restrict__ gate_fn_b,
                                                   const float* __restrict__ mwT,
                                                   const float* __restrict__ merger_b,
                                                   float* __restrict__ out) {
    int lane = threadIdx.x & 63, wv = threadIdx.x >> 6;
    int n = blockIdx.x * 4 + wv;
    if (n >= NN) return;
    int rs = row_start[n], re = row_start[n + 1];
    float4 ern = ((const float4*)er)[n];
    float x0 = x[(size_t)n * 128 + lane], x1 = x[(size_t)n * 128 + 64 + lane];

    float mz0 = -INFINITY, mz1 = -INFINITY, sx0 = 0.f, sx1 = 0.f;
    float e0m = -INFINITY, e1m = -INFINITY, e2m = -INFINITY, e3m = -INFINITY;
    for (int idx = rs; idx < re; ++idx) {
        int s = src_sorted[idx];
        const float* yr = y + (size_t)s * JTOT;
        const float* xr = x + (size_t)s * 128;
        float m0 = yr[256 + lane], m1 = yr[320 + lane];
        float a0 = xr[lane], a1 = xr[64 + lane];
        float4 e4 = ((const float4*)el)[s];
        mz0 = fmaxf(mz0, m0); mz1 = fmaxf(mz1, m1);
        sx0 += a0; sx1 += a1;
        float t;
        t = e4.x + ern.x; t = (t > 0.f) ? t : 0.2f * t; e0m = fmaxf(e0m, t);
        t = e4.y + ern.y; t = (t > 0.f) ? t : 0.2f * t; e1m = fmaxf(e1m, t);
        t = e4.z + ern.z; t = (t > 0.f) ? t : 0.2f * t; e2m = fmaxf(e2m, t);
        t = e4.w + ern.w; t = (t > 0.f) ? t : 0.2f * t; e3m = fmaxf(e3m, t);
    }
    if (re == rs) { mz0 = mz1 = 0.f; e0m = e1m = e2m = e3m = 0.f; }

    float se0 = 0, se1 = 0, se2 = 0, se3 = 0;
    float ac0 = 0, ac1 = 0, ac2 = 0, ac3 = 0;
    for (int idx = rs; idx < re; ++idx) {
        int s = src_sorted[idx];
        float wgt = w_sorted[idx];
        float4 e4 = ((const float4*)el)[s];
        const float* yr = y + (size_t)s * JTOT;
        float t, ex;
        t = e4.x + ern.x; t = (t > 0.f) ? t : 0.2f * t; ex = __expf(t - e0m); se0 += ex; ac0 += ex * wgt * yr[lane];
        t = e4.y + ern.y; t = (t > 0.f) ? t : 0.2f * t; ex = __expf(t - e1m); se1 += ex; ac1 += ex * wgt * yr[64 + lane];
        t = e4.z + ern.z; t = (t > 0.f) ? t : 0.2f * t; ex = __expf(t - e2m); se2 += ex; ac2 += ex * wgt * yr[128 + lane];
        t = e4.w + ern.w; t = (t > 0.f) ? t : 0.2f * t; ex = __expf(t - e3m); se3 += ex; ac3 += ex * wgt * yr[192 + lane];
    }
    se0 = fmaxf(se0, 1e-30f); se1 = fmaxf(se1, 1e-30f);
    se2 = fmaxf(se2, 1e-30f); se3 = fmaxf(se3, 1e-30f);

    float deg = (float)(re - rs);
    float invd = 1.0f / fmaxf(deg, 1.0f);
    float mn0 = sx0 * invd, mn1 = sx1 * invd;

    float gate[4];
    #pragma unroll
    for (int h = 0; h < 4; ++h) {
        const float* gw = gate_fn_w + h * 384;
        float p = gw[lane] * x0 + gw[64 + lane] * x1 + gw[128 + lane] * mz0
                + gw[192 + lane] * mz1 + gw[256 + lane] * mn0 + gw[320 + lane] * mn1;
        #pragma unroll
        for (int o = 1; o < 64; o <<= 1) p += __shfl_xor(p, o, 64);
        gate[h] = 1.0f / (1.0f + __expf(-(p + gate_fn_b[h])));
    }

    float gated = 0.25f * (gate[0] * ac0 / se0 + gate[1] * ac1 / se1
                         + gate[2] * ac2 / se2 + gate[3] * ac3 / se3);

    float val = merger_b[lane];
    #pragma unroll
    for (int i = 0; i < 64; ++i) val += __shfl(x0, i, 64) * mwT[i * 64 + lane];
    #pragma unroll
    for (int i = 0; i < 64; ++i) val += __shfl(x1, i, 64) * mwT[(64 + i) * 64 + lane];
    #pragma unroll
    for (int i = 0; i < 64; ++i) val += __shfl(gated, i, 64) * mwT[(128 + i) * 64 + lane];
    out[(size_t)n * 64 + lane] = val;
}

extern "C" void kernel_launch(void* const* d_in, const int* in_sizes, int n_in,
                              void* d_out, int out_size, void* d_ws, size_t ws_size,
                              hipStream_t stream) {
    const float* x         = (const float*)d_in[0];
    const int*   src       = (const int*)d_in[1];
    const int*   dst       = (const int*)d_in[2];
    const float* weight    = (const float*)d_in[3];
    const float* fc_w      = (const float*)d_in[4];
    const float* attn_l    = (const float*)d_in[5];
    const float* attn_r    = (const float*)d_in[6];
    const float* gate_m_w  = (const float*)d_in[7];
    const float* gate_m_b  = (const float*)d_in[8];
    const float* gate_fn_w = (const float*)d_in[9];
    const float* gate_fn_b = (const float*)d_in[10];
    const float* merger_w  = (const float*)d_in[11];
    const float* merger_b  = (const float*)d_in[12];
    float* out = (float*)d_out;

    char* p = (char*)d_ws;
    auto alloc = [&](size_t bytes) {
        char* r = p;
        p += (bytes + 255) & ~(size_t)255;
        return r;
    };
    float* y          = (float*)alloc((size_t)NN * JTOT * 4);
    float* el         = (float*)alloc((size_t)NN * 4 * 4);
    float* er         = (float*)alloc((size_t)NN * 4 * 4);
    int*   counts     = (int*)alloc((size_t)NN * 4);
    int*   row_start  = (int*)alloc((size_t)(NN + 1) * 4);
    int*   cursor     = (int*)alloc((size_t)NN * 4);
    int*   src_sorted = (int*)alloc((size_t)EE * 4);
    float* w_sorted   = (float*)alloc((size_t)EE * 4);
    float* mwT        = (float*)alloc((size_t)192 * 64 * 4);

    prep_kernel<<<(NN + 255) / 256, 256, 0, stream>>>(counts, merger_w, mwT);
    count_kernel<<<1024, 256, 0, stream>>>(dst, counts);
    scan_kernel<<<1, 1024, 0, stream>>>(counts, row_start, cursor);
    scatter_kernel<<<1024, 256, 0, stream>>>(src, dst, weight, cursor, src_sorted, w_sorted);
    gemm_kernel<<<dim3(168, 6), 256, 0, stream>>>(x, fc_w, gate_m_w, gate_m_b, y);
    elr_kernel<<<NN / 4, 256, 0, stream>>>(y, attn_l, attn_r, el, er);
    node_kernel<<<NN / 4, 256, 0, stream>>>(x, y, el, er, row_start, src_sorted, w_sorted,
                                            gate_fn_w, gate_fn_b, mwT, merger_b, out);
}

// Round 2
// 563.293 us; speedup vs baseline: 1.4397x; 1.4397x over previous
//
#include <hip/hip_runtime.h>
#include <math.h>

#define NN 50000
#define EE 800000
#define JTOT 384   // 256 feat + 128 mz

typedef short s8v __attribute__((ext_vector_type(8)));
typedef float f4v __attribute__((ext_vector_type(4)));

__device__ inline unsigned short f2bf(float f) {
    unsigned u = __float_as_uint(f);
    unsigned r = (u + 0x7FFFu + ((u >> 16) & 1u)) >> 16;   // RTNE
    return (unsigned short)r;
}

// ---------------- prep: zero degree counts + transpose merger_w ----------------
__global__ void prep_kernel(int* counts, const float* merger_w, float* mwT) {
    int i = blockIdx.x * blockDim.x + threadIdx.x;
    if (i < NN) counts[i] = 0;
    if (i < 192 * 64) {
        int r = i >> 6, c = i & 63;
        mwT[i] = merger_w[c * 192 + r];
    }
}

// ---------------- bf16 conversion: x -> xb, [fc_w;gate_m_w] -> wb ----------------
__global__ void cvt_kernel(const float* __restrict__ x, const float* __restrict__ fc_w,
                           const float* __restrict__ gate_m_w,
                           unsigned short* __restrict__ xb, unsigned short* __restrict__ wb) {
    int stride = gridDim.x * blockDim.x;
    int tid = blockIdx.x * blockDim.x + threadIdx.x;
    const int total_x4 = NN * 128 / 4;
    for (int i = tid; i < total_x4; i += stride) {
        float4 v = ((const float4*)x)[i];
        ushort4 o;
        o.x = f2bf(v.x); o.y = f2bf(v.y); o.z = f2bf(v.z); o.w = f2bf(v.w);
        ((ushort4*)xb)[i] = o;
    }
    for (int i = tid; i < 384 * 128; i += stride)
        wb[i] = f2bf(i < 256 * 128 ? fc_w[i] : gate_m_w[i - 256 * 128]);
}

// ---------------- CSR build ----------------
__global__ void count_kernel(const int* __restrict__ dst, int* counts) {
    for (int i = blockIdx.x * blockDim.x + threadIdx.x; i < EE; i += gridDim.x * blockDim.x)
        atomicAdd(&counts[dst[i]], 1);
}

__global__ __launch_bounds__(1024) void scan_kernel(const int* __restrict__ counts,
                                                    int* row_start, int* cursor) {
    __shared__ int sm[1024];
    const int per = (NN + 1023) / 1024;
    int t = threadIdx.x;
    int base = t * per;
    int s = 0;
    for (int i = 0; i < per; ++i) {
        int idx = base + i;
        if (idx < NN) s += counts[idx];
    }
    sm[t] = s;
    __syncthreads();
    for (int off = 1; off < 1024; off <<= 1) {
        int v = (t >= off) ? sm[t - off] : 0;
        __syncthreads();
        sm[t] += v;
        __syncthreads();
    }
    int run = sm[t] - s;
    for (int i = 0; i < per; ++i) {
        int idx = base + i;
        if (idx < NN) {
            row_start[idx] = run;
            cursor[idx] = run;
            run += counts[idx];
        }
    }
    if (t == 1023) row_start[NN] = sm[1023];
}

__global__ void scatter_kernel(const int* __restrict__ src, const int* __restrict__ dst,
                               const float* __restrict__ weight, int* cursor,
                               int* src_sorted, float* w_sorted) {
    for (int i = blockIdx.x * blockDim.x + threadIdx.x; i < EE; i += gridDim.x * blockDim.x) {
        int pos = atomicAdd(&cursor[dst[i]], 1);
        src_sorted[pos] = src[i];
        w_sorted[pos] = weight[i];
    }
}

// ---------------- MFMA GEMM: y[n][0:256]=feat, y[n][256:384]=mz (+bias) ----------------
// 128x128 tile, K=128 fully staged. 4 waves in 2x2; each wave: 64x64 out = 4x4 frags.
__global__ __launch_bounds__(256) void gemm_mfma(const unsigned short* __restrict__ xb,
                                                 const unsigned short* __restrict__ wb,
                                                 const float* __restrict__ gate_m_b,
                                                 float* __restrict__ y) {
    __shared__ unsigned short lx[128 * 136];   // pad 8 halves -> 272B stride (2-way = free)
    __shared__ unsigned short lw[128 * 136];
    int tid = threadIdx.x;
    int row0 = blockIdx.x * 128;
    int jc = blockIdx.y;   // 0..2, 128 output cols each

    #pragma unroll
    for (int c = 0; c < 8; ++c) {
        int chunk = c * 256 + tid;           // 0..2047 : 16B chunks of a 128x128 bf16 tile
        int r = chunk >> 4, seg = chunk & 15;
        int gr = row0 + r; if (gr >= NN) gr = NN - 1;
        *(s8v*)&lx[r * 136 + seg * 8] = *(const s8v*)&xb[(size_t)gr * 128 + seg * 8];
        *(s8v*)&lw[r * 136 + seg * 8] = *(const s8v*)&wb[(size_t)(jc * 128 + r) * 128 + seg * 8];
    }
    __syncthreads();

    int lane = tid & 63, w = tid >> 6;
    int wr = w >> 1, wc = w & 1;
    int lrow = lane & 15, lhi = lane >> 4;
    f4v acc[4][4] = {};
    const unsigned short* pax = &lx[(wr * 64 + lrow) * 136 + lhi * 8];
    const unsigned short* pbw = &lw[(wc * 64 + lrow) * 136 + lhi * 8];
    #pragma unroll
    for (int kk = 0; kk < 4; ++kk) {
        s8v a[4], b[4];
        #pragma unroll
        for (int mi = 0; mi < 4; ++mi) a[mi] = *(const s8v*)(pax + mi * 16 * 136 + kk * 32);
        #pragma unroll
        for (int ni = 0; ni < 4; ++ni) b[ni] = *(const s8v*)(pbw + ni * 16 * 136 + kk * 32);
        #pragma unroll
        for (int mi = 0; mi < 4; ++mi)
            #pragma unroll
            for (int ni = 0; ni < 4; ++ni)
                acc[mi][ni] = __builtin_amdgcn_mfma_f32_16x16x32_bf16(a[mi], b[ni], acc[mi][ni], 0, 0, 0);
    }

    #pragma unroll
    for (int ni = 0; ni < 4; ++ni) {
        int gcol = jc * 128 + wc * 64 + ni * 16 + lrow;
        float bias = (gcol >= 256) ? gate_m_b[gcol - 256] : 0.0f;
        #pragma unroll
        for (int mi = 0; mi < 4; ++mi) {
            int grow0 = row0 + wr * 64 + mi * 16 + lhi * 4;
            #pragma unroll
            for (int rg = 0; rg < 4; ++rg) {
                int grow = grow0 + rg;
                if (grow < NN) y[(size_t)grow * JTOT + gcol] = acc[mi][ni][rg] + bias;
            }
        }
    }
}

// ---------------- el/er per node ----------------
__global__ __launch_bounds__(256) void elr_kernel(const float* __restrict__ y,
                                                  const float* __restrict__ attn_l,
                                                  const float* __restrict__ attn_r,
                                                  float* el, float* er) {
    int lane = threadIdx.x & 63, wv = threadIdx.x >> 6;
    int n = blockIdx.x * 4 + wv;
    if (n >= NN) return;
    const float* f = y + (size_t)n * JTOT;
    float pl[4], pr[4];
    #pragma unroll
    for (int h = 0; h < 4; ++h) {
        float fv = f[h * 64 + lane];
        pl[h] = fv * attn_l[h * 64 + lane];
        pr[h] = fv * attn_r[h * 64 + lane];
    }
    #pragma unroll
    for (int h = 0; h < 4; ++h) {
        #pragma unroll
        for (int o = 1; o < 64; o <<= 1) {
            pl[h] += __shfl_xor(pl[h], o, 64);
            pr[h] += __shfl_xor(pr[h], o, 64);
        }
    }
    if (lane == 0) {
        ((float4*)el)[n] = make_float4(pl[0], pl[1], pl[2], pl[3]);
        ((float4*)er)[n] = make_float4(pr[0], pr[1], pr[2], pr[3]);
    }
}

// ---------------- main per-node aggregation + gate + merger ----------------
__global__ __launch_bounds__(256) void node_kernel(const float* __restrict__ x,
                                                   const float* __restrict__ y,
                                                   const float* __restrict__ el,
                                                   const float* __restrict__ er,
                                                   const int* __restrict__ row_start,
                                                   const int* __restrict__ src_sorted,
                                                   const float* __restrict__ w_sorted,
                                                   const float* __restrict__ gate_fn_w,
                                                   const float* __restrict__ gate_fn_b,
                                                   const float* __restrict__ mwT,
                                                   const float* __restrict__ merger_b,
                                                   float* __restrict__ out) {
    int lane = threadIdx.x & 63, wv = threadIdx.x >> 6;
    int n = blockIdx.x * 4 + wv;
    if (n >= NN) return;
    int rs = row_start[n], re = row_start[n + 1];
    float4 ern = ((const float4*)er)[n];
    float x0 = x[(size_t)n * 128 + lane], x1 = x[(size_t)n * 128 + 64 + lane];

    float mz0 = -INFINITY, mz1 = -INFINITY, sx0 = 0.f, sx1 = 0.f;
    float e0m = -INFINITY, e1m = -INFINITY, e2m = -INFINITY, e3m = -INFINITY;
    for (int idx = rs; idx < re; ++idx) {
        int s = src_sorted[idx];
        const float* yr = y + (size_t)s * JTOT;
        const float* xr = x + (size_t)s * 128;
        float m0 = yr[256 + lane], m1 = yr[320 + lane];
        float a0 = xr[lane], a1 = xr[64 + lane];
        float4 e4 = ((const float4*)el)[s];
        mz0 = fmaxf(mz0, m0); mz1 = fmaxf(mz1, m1);
        sx0 += a0; sx1 += a1;
        float t;
        t = e4.x + ern.x; t = (t > 0.f) ? t : 0.2f * t; e0m = fmaxf(e0m, t);
        t = e4.y + ern.y; t = (t > 0.f) ? t : 0.2f * t; e1m = fmaxf(e1m, t);
        t = e4.z + ern.z; t = (t > 0.f) ? t : 0.2f * t; e2m = fmaxf(e2m, t);
        t = e4.w + ern.w; t = (t > 0.f) ? t : 0.2f * t; e3m = fmaxf(e3m, t);
    }
    if (re == rs) { mz0 = mz1 = 0.f; e0m = e1m = e2m = e3m = 0.f; }

    float se0 = 0, se1 = 0, se2 = 0, se3 = 0;
    float ac0 = 0, ac1 = 0, ac2 = 0, ac3 = 0;
    for (int idx = rs; idx < re; ++idx) {
        int s = src_sorted[idx];
        float wgt = w_sorted[idx];
        float4 e4 = ((const float4*)el)[s];
        const float* yr = y + (size_t)s * JTOT;
        float t, ex;
        t = e4.x + ern.x; t = (t > 0.f) ? t : 0.2f * t; ex = __expf(t - e0m); se0 += ex; ac0 += ex * wgt * yr[lane];
        t = e4.y + ern.y; t = (t > 0.f) ? t : 0.2f * t; ex = __expf(t - e1m); se1 += ex; ac1 += ex * wgt * yr[64 + lane];
        t = e4.z + ern.z; t = (t > 0.f) ? t : 0.2f * t; ex = __expf(t - e2m); se2 += ex; ac2 += ex * wgt * yr[128 + lane];
        t = e4.w + ern.w; t = (t > 0.f) ? t : 0.2f * t; ex = __expf(t - e3m); se3 += ex; ac3 += ex * wgt * yr[192 + lane];
    }
    se0 = fmaxf(se0, 1e-30f); se1 = fmaxf(se1, 1e-30f);
    se2 = fmaxf(se2, 1e-30f); se3 = fmaxf(se3, 1e-30f);

    float deg = (float)(re - rs);
    float invd = 1.0f / fmaxf(deg, 1.0f);
    float mn0 = sx0 * invd, mn1 = sx1 * invd;

    float gate[4];
    #pragma unroll
    for (int h = 0; h < 4; ++h) {
        const float* gw = gate_fn_w + h * 384;
        float p = gw[lane] * x0 + gw[64 + lane] * x1 + gw[128 + lane] * mz0
                + gw[192 + lane] * mz1 + gw[256 + lane] * mn0 + gw[320 + lane] * mn1;
        #pragma unroll
        for (int o = 1; o < 64; o <<= 1) p += __shfl_xor(p, o, 64);
        gate[h] = 1.0f / (1.0f + __expf(-(p + gate_fn_b[h])));
    }

    float gated = 0.25f * (gate[0] * ac0 / se0 + gate[1] * ac1 / se1
                         + gate[2] * ac2 / se2 + gate[3] * ac3 / se3);

    float val = merger_b[lane];
    #pragma unroll
    for (int i = 0; i < 64; ++i) val += __shfl(x0, i, 64) * mwT[i * 64 + lane];
    #pragma unroll
    for (int i = 0; i < 64; ++i) val += __shfl(x1, i, 64) * mwT[(64 + i) * 64 + lane];
    #pragma unroll
    for (int i = 0; i < 64; ++i) val += __shfl(gated, i, 64) * mwT[(128 + i) * 64 + lane];
    out[(size_t)n * 64 + lane] = val;
}

extern "C" void kernel_launch(void* const* d_in, const int* in_sizes, int n_in,
                              void* d_out, int out_size, void* d_ws, size_t ws_size,
                              hipStream_t stream) {
    const float* x         = (const float*)d_in[0];
    const int*   src       = (const int*)d_in[1];
    const int*   dst       = (const int*)d_in[2];
    const float* weight    = (const float*)d_in[3];
    const float* fc_w      = (const float*)d_in[4];
    const float* attn_l    = (const float*)d_in[5];
    const float* attn_r    = (const float*)d_in[6];
    const float* gate_m_w  = (const float*)d_in[7];
    const float* gate_m_b  = (const float*)d_in[8];
    const float* gate_fn_w = (const float*)d_in[9];
    const float* gate_fn_b = (const float*)d_in[10];
    const float* merger_w  = (const float*)d_in[11];
    const float* merger_b  = (const float*)d_in[12];
    float* out = (float*)d_out;

    char* p = (char*)d_ws;
    auto alloc = [&](size_t bytes) {
        char* r = p;
        p += (bytes + 255) & ~(size_t)255;
        return r;
    };
    float* y          = (float*)alloc((size_t)NN * JTOT * 4);
    float* el         = (float*)alloc((size_t)NN * 4 * 4);
    float* er         = (float*)alloc((size_t)NN * 4 * 4);
    int*   counts     = (int*)alloc((size_t)NN * 4);
    int*   row_start  = (int*)alloc((size_t)(NN + 1) * 4);
    int*   cursor     = (int*)alloc((size_t)NN * 4);
    int*   src_sorted = (int*)alloc((size_t)EE * 4);
    float* w_sorted   = (float*)alloc((size_t)EE * 4);
    float* mwT        = (float*)alloc((size_t)192 * 64 * 4);
    unsigned short* xb = (unsigned short*)alloc((size_t)NN * 128 * 2);
    unsigned short* wb = (unsigned short*)alloc((size_t)384 * 128 * 2);

    prep_kernel<<<(NN + 255) / 256, 256, 0, stream>>>(counts, merger_w, mwT);
    cvt_kernel<<<1024, 256, 0, stream>>>(x, fc_w, gate_m_w, xb, wb);
    count_kernel<<<1024, 256, 0, stream>>>(dst, counts);
    scan_kernel<<<1, 1024, 0, stream>>>(counts, row_start, cursor);
    scatter_kernel<<<1024, 256, 0, stream>>>(src, dst, weight, cursor, src_sorted, w_sorted);
    gemm_mfma<<<dim3((NN + 127) / 128, 3), 256, 0, stream>>>(xb, wb, gate_m_b, y);
    elr_kernel<<<NN / 4, 256, 0, stream>>>(y, attn_l, attn_r, el, er);
    node_kernel<<<NN / 4, 256, 0, stream>>>(x, y, el, er, row_start, src_sorted, w_sorted,
                                            gate_fn_w, gate_fn_b, mwT, merger_b, out);
}